// Round 12
// baseline (280.336 us; speedup 1.0000x reference)
//
#include <hip/hip_runtime.h>

#define OUT_SZ 299
#define PLANE (OUT_SZ * OUT_SZ)   // 89401
#define RPB 13                    // output rows per block: 13 * 23 = 299
#define CHUNKS 23
#define TSTRIDE 201               // tmp row stride in dwords (odd; >= wcI+1, wcI<=199)

__global__ __launch_bounds__(320) void crop_resize_kernel(
    const float* __restrict__ x,   // (32, 3, 299, 299)
    const int*   __restrict__ f,   // (32, 16, 4) = tlx, tly, brx, bry
    float*       __restrict__ out) // (32, 16, 3, 299, 299)
{
    __shared__ float tmp[RPB * TSTRIDE];   // 10452 B: row-interped crop rows

    const int t     = threadIdx.x;
    const int chunk = blockIdx.x;    // 0..22
    const int sg    = blockIdx.y;    // s*16 + g
    const int s     = sg >> 4;

    // Box is block-uniform -> scalar loads.
    const int4 box = *reinterpret_cast<const int4*>(f + (size_t)sg * 4);
    const int tlx = box.x, tly = box.y, brx = box.z, bry = box.w;
    const int hcI = brx - tlx, wcI = bry - tly;
    const float hc = (float)hcI, wc = (float)wcI;

    const int i0 = chunk * RPB;

    // Lane table: lanes 0..12 of EVERY wave hold row info for output row i0+rr.
    // Uniform control flow (all threads execute).
    const int lane = t & 63;
    int v_r0e, v_r1e;
    float v_wr;
    {
        float sr  = fminf(fmaxf(((float)(i0 + lane) + 0.5f) * hc / (float)OUT_SZ
                                - 0.5f, 0.0f), hc - 1.0f);
        float r0f = floorf(sr);
        v_wr = sr - r0f;
        int r0l = (int)r0f;
        int r1l = min(r0l + 1, hcI - 1);
        v_r0e = (r0l + tlx) * OUT_SZ + tly;   // plane-local offset of crop row r0
        v_r1e = (r1l + tlx) * OUT_SZ + tly;
    }

    // Hoist ALL readlanes into uniform control flow (convergent-op safety).
    // 39 wave-uniform scalars, statically indexed -> SGPRs (fits, as in R9).
    int   sr0e[RPB], sr1e[RPB];
    float srw[RPB];
    #pragma unroll
    for (int rr = 0; rr < RPB; ++rr) {
        sr0e[rr] = __builtin_amdgcn_readlane(v_r0e, rr);
        sr1e[rr] = __builtin_amdgcn_readlane(v_r1e, rr);
        srw[rr]  = __int_as_float(
                       __builtin_amdgcn_readlane(__float_as_int(v_wr), rr));
    }

    // Per-output-column precompute (registers only, channel-independent).
    float sc  = fminf(fmaxf(((float)t + 0.5f) * wc / (float)OUT_SZ - 0.5f,
                            0.0f), wc - 1.0f);
    float c0f = floorf(sc);
    const int   c0  = (int)c0f;          // crop-local, in [0, wcI-1]
    const float wcl = sc - c0f;
    const int   jl  = min(t, wcI - 1);   // phase-1 load col (t==wcI -> pad dup)

    const float* __restrict__ imgS = x   + (size_t)s  * 3 * PLANE;
    float*       __restrict__ outS = out + (size_t)sg * 3 * PLANE
                                   + (size_t)i0 * OUT_SZ + t;

    // Channel loop: geometry computed once, reused 3x. Barriers uniform.
    for (int ch = 0; ch < 3; ++ch) {
        const float* __restrict__ img = imgS + (size_t)ch * PLANE;

        // Phase 1: vertical (row) interp over crop columns — COALESCED loads.
        if (t <= wcI) {                  // plain loads/stores only inside
            #pragma unroll
            for (int rr = 0; rr < RPB; ++rr) {
                float a = img[sr0e[rr] + jl];    // scalar base + lane index
                float b = img[sr1e[rr] + jl];
                tmp[rr * TSTRIDE + t] = a + srw[rr] * (b - a);
            }
        }
        __syncthreads();

        // Phase 2: horizontal (col) interp — ds_read2_b32 + 2 FMA + store.
        if (t < OUT_SZ) {
            float* __restrict__ orow = outS + (size_t)ch * PLANE;
            #pragma unroll
            for (int rr = 0; rr < RPB; ++rr) {
                const float* p = tmp + rr * TSTRIDE + c0;
                float hA = p[0];
                float hB = p[1];   // adjacent dword; pad col makes c1-clamp exact
                orow[(size_t)rr * OUT_SZ] = hA + wcl * (hB - hA);
            }
        }
        if (ch < 2) __syncthreads();     // protect tmp before next channel
    }
}

extern "C" void kernel_launch(void* const* d_in, const int* in_sizes, int n_in,
                              void* d_out, int out_size, void* d_ws, size_t ws_size,
                              hipStream_t stream) {
    const float* x   = (const float*)d_in[0];  // (32,3,299,299) fp32
    const int*   f   = (const int*)  d_in[1];  // (32,16,4) int32
    float*       out = (float*)d_out;          // (32,16,3,299,299) fp32

    dim3 grid(CHUNKS, 32 * 16);
    crop_resize_kernel<<<grid, 320, 0, stream>>>(x, f, out);
}

// Round 13
// 146.759 us; speedup vs baseline: 1.9102x; 1.9102x over previous
//
#include <hip/hip_runtime.h>

#define OUT_SZ 299
#define PLANE (OUT_SZ * OUT_SZ)   // 89401
#define RPB 13                    // output rows per block: 13 * 23 = 299
#define CHUNKS 23
#define TSTRIDE 201               // tmp row stride in dwords (odd; >= wcI+1, wcI<=199)

__global__ __launch_bounds__(320) void crop_resize_kernel(
    const float* __restrict__ x,   // (32, 3, 299, 299)
    const int*   __restrict__ f,   // (32, 16, 4) = tlx, tly, brx, bry
    float*       __restrict__ out) // (32, 16, 3, 299, 299)
{
    __shared__ float tmp[3][RPB * TSTRIDE];   // 31356 B: 3 channels of crop rows

    const int t     = threadIdx.x;
    const int chunk = blockIdx.x;    // 0..22
    const int sg    = blockIdx.y;    // s*16 + g
    const int s     = sg >> 4;

    // Box is block-uniform -> scalar loads.
    const int4 box = *reinterpret_cast<const int4*>(f + (size_t)sg * 4);
    const int tlx = box.x, tly = box.y, brx = box.z, bry = box.w;
    const int hcI = brx - tlx, wcI = bry - tly;
    const float hc = (float)hcI, wc = (float)wcI;

    const int i0 = chunk * RPB;

    // Lane table: lanes 0..12 of EVERY wave hold row info for output row i0+rr.
    // Uniform control flow (all threads execute).
    const int lane = t & 63;
    int v_r0e, v_r1e;
    float v_wr;
    {
        float sr  = fminf(fmaxf(((float)(i0 + lane) + 0.5f) * hc / (float)OUT_SZ
                                - 0.5f, 0.0f), hc - 1.0f);
        float r0f = floorf(sr);
        v_wr = sr - r0f;
        int r0l = (int)r0f;
        int r1l = min(r0l + 1, hcI - 1);
        v_r0e = (r0l + tlx) * OUT_SZ + tly;   // plane-local offset of crop row r0
        v_r1e = (r1l + tlx) * OUT_SZ + tly;
    }

    // Hoist ALL readlanes into uniform control flow (convergent-op safety).
    // 39 wave-uniform scalars, statically indexed -> SGPRs (fits, as in R9).
    int   sr0e[RPB], sr1e[RPB];
    float srw[RPB];
    #pragma unroll
    for (int rr = 0; rr < RPB; ++rr) {
        sr0e[rr] = __builtin_amdgcn_readlane(v_r0e, rr);
        sr1e[rr] = __builtin_amdgcn_readlane(v_r1e, rr);
        srw[rr]  = __int_as_float(
                       __builtin_amdgcn_readlane(__float_as_int(v_wr), rr));
    }

    // Per-output-column precompute (registers only, channel-independent).
    float sc  = fminf(fmaxf(((float)t + 0.5f) * wc / (float)OUT_SZ - 0.5f,
                            0.0f), wc - 1.0f);
    float c0f = floorf(sc);
    const int   c0  = (int)c0f;          // crop-local, in [0, wcI-1]
    const float wcl = sc - c0f;
    const int   jl  = min(t, wcI - 1);   // phase-1 load col (t==wcI -> pad dup)

    const float* __restrict__ imgS = x   + (size_t)s  * 3 * PLANE;
    float*       __restrict__ outS = out + (size_t)sg * 3 * PLANE
                                   + (size_t)i0 * OUT_SZ + t;

    // Phase 1: vertical (row) interp, ALL 3 channels, COALESCED loads.
    // No convergent ops inside the divergent guard; single barrier total.
    if (t <= wcI) {
        for (int ch = 0; ch < 3; ++ch) {
            const float* __restrict__ img = imgS + (size_t)ch * PLANE;
            #pragma unroll
            for (int rr = 0; rr < RPB; ++rr) {
                float a = img[sr0e[rr] + jl];    // scalar base + lane index
                float b = img[sr1e[rr] + jl];
                tmp[ch][rr * TSTRIDE + t] = a + srw[rr] * (b - a);
            }
        }
    }
    __syncthreads();
    if (t >= OUT_SZ) return;

    // Phase 2: horizontal (col) interp, ALL 3 channels.
    for (int ch = 0; ch < 3; ++ch) {
        float* __restrict__ orow = outS + (size_t)ch * PLANE;
        const float* __restrict__ tc = tmp[ch] + c0;
        #pragma unroll
        for (int rr = 0; rr < RPB; ++rr) {
            const float* p = tc + rr * TSTRIDE;
            float hA = p[0];
            float hB = p[1];   // adjacent dword; pad col makes c1-clamp exact
            orow[(size_t)rr * OUT_SZ] = hA + wcl * (hB - hA);
        }
    }
}

extern "C" void kernel_launch(void* const* d_in, const int* in_sizes, int n_in,
                              void* d_out, int out_size, void* d_ws, size_t ws_size,
                              hipStream_t stream) {
    const float* x   = (const float*)d_in[0];  // (32,3,299,299) fp32
    const int*   f   = (const int*)  d_in[1];  // (32,16,4) int32
    float*       out = (float*)d_out;          // (32,16,3,299,299) fp32

    dim3 grid(CHUNKS, 32 * 16);
    crop_resize_kernel<<<grid, 320, 0, stream>>>(x, f, out);
}

// Round 14
// 124.055 us; speedup vs baseline: 2.2598x; 1.1830x over previous
//
#include <hip/hip_runtime.h>

#define OUT_SZ 299
#define PLANE (OUT_SZ * OUT_SZ)   // 89401
#define RPB 13                    // output rows per block: 13 * 23 = 299
#define CHUNKS 23
#define TSTRIDE 201               // tmp row stride in dwords (odd; >= wcI+1, wcI<=199)
#define BLK_PER_IMG (16 * 3 * CHUNKS)   // 1104 blocks per image
#define NXCD 8

__global__ __launch_bounds__(320) void crop_resize_kernel(
    const float* __restrict__ x,   // (32, 3, 299, 299)
    const int*   __restrict__ f,   // (32, 16, 4) = tlx, tly, brx, bry
    float*       __restrict__ out) // (32, 16, 3, 299, 299)
{
    __shared__ float tmp[RPB * TSTRIDE];   // 10452 B: row-interped crop rows

    // --- XCD-aware swizzle: all 1104 blocks of an image land on one XCD ---
    // HW: block L -> XCD L%8 (round-robin). XCD k processes images {k, k+8, k+16, k+24}.
    const int L       = blockIdx.x;          // 0..35327
    const int xcd     = L & (NXCD - 1);
    const int W       = L >> 3;              // 0..4415
    const int img_grp = W / BLK_PER_IMG;     // 0..3
    const int within  = W - img_grp * BLK_PER_IMG;   // 0..1103
    const int s       = xcd + (img_grp << 3);        // image 0..31
    const int sgl     = within / (3 * CHUNKS);       // crop 0..15
    const int rem     = within - sgl * (3 * CHUNKS);
    const int c       = rem / CHUNKS;                // channel 0..2
    const int chunk   = rem - c * CHUNKS;            // 0..22
    const int sg      = (s << 4) + sgl;

    const int t = threadIdx.x;

    // Box is block-uniform -> scalar loads.
    const int4 box = *reinterpret_cast<const int4*>(f + (size_t)sg * 4);
    const int tlx = box.x, tly = box.y, brx = box.z, bry = box.w;
    const int hcI = brx - tlx, wcI = bry - tly;
    const float hc = (float)hcI, wc = (float)wcI;

    const int i0 = chunk * RPB;

    // Lane table: lanes 0..12 of EVERY wave hold row info for output row i0+rr.
    // Uniform control flow (all threads execute).
    const int lane = t & 63;
    int v_r0e, v_r1e;
    float v_wr;
    {
        float sr  = fminf(fmaxf(((float)(i0 + lane) + 0.5f) * hc / (float)OUT_SZ
                                - 0.5f, 0.0f), hc - 1.0f);
        float r0f = floorf(sr);
        v_wr = sr - r0f;
        int r0l = (int)r0f;
        int r1l = min(r0l + 1, hcI - 1);
        v_r0e = (r0l + tlx) * OUT_SZ + tly;   // plane-local offset of crop row r0
        v_r1e = (r1l + tlx) * OUT_SZ + tly;
    }

    // Hoist ALL readlanes into uniform control flow (convergent-op safety).
    // 39 wave-uniform scalars, statically indexed -> SGPRs.
    int   sr0e[RPB], sr1e[RPB];
    float srw[RPB];
    #pragma unroll
    for (int rr = 0; rr < RPB; ++rr) {
        sr0e[rr] = __builtin_amdgcn_readlane(v_r0e, rr);
        sr1e[rr] = __builtin_amdgcn_readlane(v_r1e, rr);
        srw[rr]  = __int_as_float(
                       __builtin_amdgcn_readlane(__float_as_int(v_wr), rr));
    }

    // Per-output-column precompute (registers only).
    float sc  = fminf(fmaxf(((float)t + 0.5f) * wc / (float)OUT_SZ - 0.5f,
                            0.0f), wc - 1.0f);
    float c0f = floorf(sc);
    const int   c0  = (int)c0f;          // crop-local, in [0, wcI-1]
    const float wcl = sc - c0f;
    const int   jl  = min(t, wcI - 1);   // phase-1 load col (t==wcI -> pad dup)

    const float* __restrict__ img = x + ((size_t)s * 3 + (size_t)c) * PLANE;

    // Phase 1: vertical (row) interp over crop columns — COALESCED loads.
    if (t <= wcI) {                      // plain loads/stores only inside
        #pragma unroll
        for (int rr = 0; rr < RPB; ++rr) {
            float a = img[sr0e[rr] + jl];    // scalar base + lane index
            float b = img[sr1e[rr] + jl];
            tmp[rr * TSTRIDE + t] = a + srw[rr] * (b - a);
        }
    }
    __syncthreads();
    if (t >= OUT_SZ) return;

    // Phase 2: horizontal (col) interp — ds_read2_b32 + 2 FMA + store per px.
    float* __restrict__ orow = out + ((size_t)sg * 3 + (size_t)c) * PLANE
                             + (size_t)i0 * OUT_SZ + t;
    #pragma unroll
    for (int rr = 0; rr < RPB; ++rr) {
        const float* p = tmp + rr * TSTRIDE + c0;
        float hA = p[0];
        float hB = p[1];   // adjacent dword; pad col makes c1-clamp exact
        orow[(size_t)rr * OUT_SZ] = hA + wcl * (hB - hA);
    }
}

extern "C" void kernel_launch(void* const* d_in, const int* in_sizes, int n_in,
                              void* d_out, int out_size, void* d_ws, size_t ws_size,
                              hipStream_t stream) {
    const float* x   = (const float*)d_in[0];  // (32,3,299,299) fp32
    const int*   f   = (const int*)  d_in[1];  // (32,16,4) int32
    float*       out = (float*)d_out;          // (32,16,3,299,299) fp32

    const int nblocks = NXCD * 4 * BLK_PER_IMG;   // 35328 = 23*3*512
    crop_resize_kernel<<<nblocks, 320, 0, stream>>>(x, f, out);
}